// Round 8
// baseline (386.667 us; speedup 1.0000x reference)
//
#include <hip/hip_runtime.h>

// MHA forward. L=S=1024, N=4, E=1024, H=16, hd=64, B=N*H=64, M=L*N=4096
// Inputs fp32, outputs fp32 (out0=attn_output 4.19M, out1=attn_weights 4.19M @+4194304).
// Round 7: 380 us. attn_ctx 124 us, MfmaUtil 5.4%/VALU 13.5% -- latency-bound:
// V-frag loads sat AFTER the lgkm fence (memory clobber blocked hoisting), so
// each s-step serialized on a ~250-900 cyc cold load. Round 8: register-level
// software pipelining (prefetch next K frags + issue V frags before the fence)
// in attn_ctx, and next-head prefetch in attn_w. Math order unchanged ->
// bit-identical numerics (absmax must stay 1.953e-3).
typedef unsigned short u16;
typedef __attribute__((ext_vector_type(8))) short short8;   // 8 bf16 (4 VGPRs)
typedef __attribute__((ext_vector_type(4))) float f32x4;    // MFMA accumulator

__device__ __forceinline__ u16 f2bf(float f) {  // RNE
  unsigned int i = __float_as_uint(f);
  i += 0x7fffu + ((i >> 16) & 1u);
  return (u16)(i >> 16);
}

__device__ __forceinline__ short8 cvt8(const float* p) {
  float4 a = ((const float4*)p)[0];
  float4 b = ((const float4*)p)[1];
  short8 r;
  r[0] = (short)f2bf(a.x); r[1] = (short)f2bf(a.y);
  r[2] = (short)f2bf(a.z); r[3] = (short)f2bf(a.w);
  r[4] = (short)f2bf(b.x); r[5] = (short)f2bf(b.y);
  r[6] = (short)f2bf(b.z); r[7] = (short)f2bf(b.w);
  return r;
}

// ---------------------------------------------------------------------------
// Kernel 0: one-shot fp32 -> bf16 conversion of q/k/v/W_in/W_out.
// ---------------------------------------------------------------------------
__global__ __launch_bounds__(256) void convert_bf16(
    const float* __restrict__ q, const float* __restrict__ k,
    const float* __restrict__ v, const float* __restrict__ Wi,
    const float* __restrict__ Wo,
    u16* __restrict__ qb, u16* __restrict__ kb, u16* __restrict__ vb,
    u16* __restrict__ Wib, u16* __restrict__ Wob)
{
  const float* src; u16* dst; int len8;
  switch (blockIdx.y) {
    case 0:  src = q;  dst = qb;  len8 = 524288; break;
    case 1:  src = k;  dst = kb;  len8 = 524288; break;
    case 2:  src = v;  dst = vb;  len8 = 524288; break;
    case 3:  src = Wi; dst = Wib; len8 = 393216; break;
    default: src = Wo; dst = Wob; len8 = 131072; break;
  }
  int stride = gridDim.x * 256;
  for (int i = blockIdx.x * 256 + threadIdx.x; i < len8; i += stride)
    *(short8*)(dst + (size_t)i * 8) = cvt8(src + (size_t)i * 8);
}

// ---------------------------------------------------------------------------
// Kernel 1: packed QKV projection, 128x128 LDS-tiled. Unchanged from round 7.
// ---------------------------------------------------------------------------
__global__ __launch_bounds__(256) void qkv_gemm(
    const u16* __restrict__ qb, const u16* __restrict__ kb,
    const u16* __restrict__ vb, const u16* __restrict__ W,
    const float* __restrict__ bias,
    u16* __restrict__ qh, u16* __restrict__ kh, u16* __restrict__ vt)
{
  __shared__ __align__(16) u16 As[128 * 40];
  __shared__ __align__(16) u16 Bs[128 * 40];

  const int tid  = threadIdx.x;
  const int wave = tid >> 6;
  const int lane = tid & 63;
  const int r    = lane & 15;
  const int q4   = lane >> 4;
  const int wm   = wave >> 1;
  const int wn   = wave & 1;

  const int jt = blockIdx.x;
  const int mt = blockIdx.y;
  const int src = jt >> 3;
  const u16* X = (src == 0) ? qb : (src == 1) ? kb : vb;
  const int m0 = mt * 128;
  const int j0 = jt * 128;

  const int trow = tid >> 2;
  const int tcol = (tid & 3) * 8;

  f32x4 acc[4][4];
  #pragma unroll
  for (int a = 0; a < 4; ++a)
    #pragma unroll
    for (int b = 0; b < 4; ++b)
      acc[a][b] = (f32x4){0.f, 0.f, 0.f, 0.f};

  for (int kk = 0; kk < 1024; kk += 32) {
    short8 a0 = *(const short8*)(X + (size_t)(m0 + trow) * 1024 + kk + tcol);
    short8 a1 = *(const short8*)(X + (size_t)(m0 + 64 + trow) * 1024 + kk + tcol);
    short8 b0 = *(const short8*)(W + (size_t)(j0 + trow) * 1024 + kk + tcol);
    short8 b1 = *(const short8*)(W + (size_t)(j0 + 64 + trow) * 1024 + kk + tcol);
    __syncthreads();
    *(short8*)(As + trow * 40 + tcol) = a0;
    *(short8*)(As + (64 + trow) * 40 + tcol) = a1;
    *(short8*)(Bs + trow * 40 + tcol) = b0;
    *(short8*)(Bs + (64 + trow) * 40 + tcol) = b1;
    __syncthreads();

    const u16* Ab = As + (wm * 64) * 40;
    const u16* Bb = Bs + (wn * 64) * 40;
    short8 af[4], bf[4];
    #pragma unroll
    for (int mi = 0; mi < 4; ++mi)
      af[mi] = *(const short8*)(Ab + (mi * 16 + r) * 40 + q4 * 8);
    #pragma unroll
    for (int ji = 0; ji < 4; ++ji)
      bf[ji] = *(const short8*)(Bb + (ji * 16 + r) * 40 + q4 * 8);
    #pragma unroll
    for (int mi = 0; mi < 4; ++mi)
      #pragma unroll
      for (int ji = 0; ji < 4; ++ji)
        acc[mi][ji] = __builtin_amdgcn_mfma_f32_16x16x32_bf16(af[mi], bf[ji], acc[mi][ji], 0, 0, 0);
  }

  #pragma unroll
  for (int mi = 0; mi < 4; ++mi) {
    #pragma unroll
    for (int ji = 0; ji < 4; ++ji) {
      #pragma unroll
      for (int rr = 0; rr < 4; ++rr) {
        int m = m0 + wm * 64 + mi * 16 + q4 * 4 + rr;
        int j = j0 + wn * 64 + ji * 16 + r;
        float v = acc[mi][ji][rr] + bias[j];
        int t = m >> 2, n = m & 3;
        int jj = j & 1023;
        int h = jj >> 6, d = jj & 63;
        int bb = n * 16 + h;
        if (src == 0)
          qh[(size_t)bb * 65536 + (size_t)t * 64 + d] = f2bf(v * 0.125f);
        else if (src == 1)
          kh[(size_t)bb * 65536 + (size_t)t * 64 + d] = f2bf(v);
        else
          vt[(size_t)bb * 65536 + (size_t)d * 1024 + t] = f2bf(v);
      }
    }
  }
}

// ---------------------------------------------------------------------------
// Kernel 2: attention context, MFMA flash-style, register-pipelined.
// Per s-step: [prefetch K(s+1), issue V(s)] -> QK(s) -> exp/P-write -> fence
// -> P-read -> PV(s). Global loads are all textually BEFORE the fence so they
// fly during exp/pack/drain. Math identical to round 7.
// ---------------------------------------------------------------------------
__global__ __launch_bounds__(256) void attn_ctx_mfma(
    const u16* __restrict__ qh, const u16* __restrict__ kh,
    const u16* __restrict__ vt, u16* __restrict__ ctx,
    float* __restrict__ Zbuf)
{
  __shared__ __align__(16) u16 Pl[4][16 * 72];
  const int tid = threadIdx.x;
  const int wv = tid >> 6, lane = tid & 63, r = lane & 15, q4 = lane >> 4;
  const int b  = blockIdx.y;
  const int lw = blockIdx.x * 64 + wv * 16;
  const int n = b >> 4, h = b & 15;

  const u16* qbase = qh + (size_t)b * 65536;
  const u16* kbase = kh + (size_t)b * 65536;
  const u16* vbase = vt + (size_t)b * 65536;
  u16* P = Pl[wv];

  short8 aq0 = *(const short8*)(qbase + (size_t)(lw + r) * 64 + q4 * 8);
  short8 aq1 = *(const short8*)(qbase + (size_t)(lw + r) * 64 + 32 + q4 * 8);

  f32x4 oc[4];
  #pragma unroll
  for (int ji = 0; ji < 4; ++ji) oc[ji] = (f32x4){0.f, 0.f, 0.f, 0.f};
  float z[4] = {0.f, 0.f, 0.f, 0.f};

  // prologue: K frags for s0 = 0
  short8 kf[8];
  #pragma unroll
  for (int ji = 0; ji < 4; ++ji) {
    kf[2 * ji]     = *(const short8*)(kbase + (size_t)(ji * 16 + r) * 64 + q4 * 8);
    kf[2 * ji + 1] = *(const short8*)(kbase + (size_t)(ji * 16 + r) * 64 + 32 + q4 * 8);
  }

  for (int s0 = 0; s0 < 1024; s0 += 64) {
    // prefetch next K tile (wraps to 0 on last iter: harmless dummy)
    const int sp = (s0 + 64) & 1023;
    short8 kn[8];
    #pragma unroll
    for (int ji = 0; ji < 4; ++ji) {
      kn[2 * ji]     = *(const short8*)(kbase + (size_t)(sp + ji * 16 + r) * 64 + q4 * 8);
      kn[2 * ji + 1] = *(const short8*)(kbase + (size_t)(sp + ji * 16 + r) * 64 + 32 + q4 * 8);
    }
    // V frags for the CURRENT tile — issued ~250+ cycles before first use
    short8 vf[8];
    #pragma unroll
    for (int ji = 0; ji < 4; ++ji) {
      vf[2 * ji]     = *(const short8*)(vbase + (size_t)(ji * 16 + r) * 1024 + s0 + q4 * 8);
      vf[2 * ji + 1] = *(const short8*)(vbase + (size_t)(ji * 16 + r) * 1024 + s0 + 32 + q4 * 8);
    }
    // QK^T
    f32x4 sc[4];
    #pragma unroll
    for (int ji = 0; ji < 4; ++ji) {
      f32x4 t = (f32x4){0.f, 0.f, 0.f, 0.f};
      t = __builtin_amdgcn_mfma_f32_16x16x32_bf16(aq0, kf[2 * ji], t, 0, 0, 0);
      t = __builtin_amdgcn_mfma_f32_16x16x32_bf16(aq1, kf[2 * ji + 1], t, 0, 0, 0);
      sc[ji] = t;
    }
    // exp, z-accum, P to LDS (C-layout row = q4*4+rr, col = ji*16+r)
    #pragma unroll
    for (int ji = 0; ji < 4; ++ji)
      #pragma unroll
      for (int rr = 0; rr < 4; ++rr) {
        float e = __expf(sc[ji][rr]);
        z[rr] += e;
        P[(q4 * 4 + rr) * 72 + ji * 16 + r] = f2bf(e);
      }
    // same-wave LDS write->read: drain LDS queue (global loads already issued)
    asm volatile("s_waitcnt lgkmcnt(0)" ::: "memory");
    short8 ap0 = *(const short8*)(P + (size_t)r * 72 + q4 * 8);
    short8 ap1 = *(const short8*)(P + (size_t)r * 72 + 32 + q4 * 8);
    #pragma unroll
    for (int ji = 0; ji < 4; ++ji) {
      oc[ji] = __builtin_amdgcn_mfma_f32_16x16x32_bf16(ap0, vf[2 * ji], oc[ji], 0, 0, 0);
      oc[ji] = __builtin_amdgcn_mfma_f32_16x16x32_bf16(ap1, vf[2 * ji + 1], oc[ji], 0, 0, 0);
    }
    #pragma unroll
    for (int i = 0; i < 8; ++i) kf[i] = kn[i];
  }

  #pragma unroll
  for (int rr = 0; rr < 4; ++rr) {
    float zz = z[rr];
    zz += __shfl_xor(zz, 1);
    zz += __shfl_xor(zz, 2);
    zz += __shfl_xor(zz, 4);
    zz += __shfl_xor(zz, 8);
    z[rr] = zz;
  }

  #pragma unroll
  for (int rr = 0; rr < 4; ++rr) {
    float inv = 1.0f / z[rr];
    int l = lw + q4 * 4 + rr;
    u16* crow = ctx + ((size_t)l * 4 + n) * 1024 + h * 64;
    #pragma unroll
    for (int ji = 0; ji < 4; ++ji)
      crow[ji * 16 + r] = f2bf(oc[ji][rr] * inv);
    if (r == 0) Zbuf[(size_t)b * 1024 + l] = z[rr];
  }
}

// ---------------------------------------------------------------------------
// Kernel 3: head-averaged attention weights, register-pipelined across heads.
// Prefetch head hh+1's q/k frags while computing head hh. Math identical.
// ---------------------------------------------------------------------------
__global__ __launch_bounds__(256) void attn_w_mfma(
    const u16* __restrict__ qh, const u16* __restrict__ kh,
    const float* __restrict__ Zbuf, float* __restrict__ out_w)
{
  __shared__ float invZ[16][64];
  const int tid = threadIdx.x;
  const int wv = tid >> 6, lane = tid & 63, r = lane & 15, q4 = lane >> 4;
  const int lt = blockIdx.x;
  const int st = blockIdx.y;
  const int n  = blockIdx.z;
  const int l0 = lt * 64;
  const int s0 = st * 64;
  const int lw = l0 + wv * 16;

  for (int i = tid; i < 1024; i += 256) {
    int hh = i >> 6, row = i & 63;
    invZ[hh][row] = 1.0f / (Zbuf[(size_t)(n * 16 + hh) * 1024 + l0 + row] * 16.0f);
  }
  __syncthreads();

  const u16* qb0 = qh + (size_t)(n * 16) * 65536;
  const u16* kb0 = kh + (size_t)(n * 16) * 65536;

  f32x4 wacc[4];
  #pragma unroll
  for (int ji = 0; ji < 4; ++ji) wacc[ji] = (f32x4){0.f, 0.f, 0.f, 0.f};

  // prologue: head 0 frags
  short8 qf0 = *(const short8*)(qb0 + (size_t)(lw + r) * 64 + q4 * 8);
  short8 qf1 = *(const short8*)(qb0 + (size_t)(lw + r) * 64 + 32 + q4 * 8);
  short8 kf[8];
  #pragma unroll
  for (int ji = 0; ji < 4; ++ji) {
    kf[2 * ji]     = *(const short8*)(kb0 + (size_t)(s0 + ji * 16 + r) * 64 + q4 * 8);
    kf[2 * ji + 1] = *(const short8*)(kb0 + (size_t)(s0 + ji * 16 + r) * 64 + 32 + q4 * 8);
  }

  for (int hh = 0; hh < 16; ++hh) {
    // prefetch next head (wraps on last iter: harmless dummy)
    const size_t hp = (size_t)((hh + 1) & 15) * 65536;
    short8 qn0 = *(const short8*)(qb0 + hp + (size_t)(lw + r) * 64 + q4 * 8);
    short8 qn1 = *(const short8*)(qb0 + hp + (size_t)(lw + r) * 64 + 32 + q4 * 8);
    short8 kn[8];
    #pragma unroll
    for (int ji = 0; ji < 4; ++ji) {
      kn[2 * ji]     = *(const short8*)(kb0 + hp + (size_t)(s0 + ji * 16 + r) * 64 + q4 * 8);
      kn[2 * ji + 1] = *(const short8*)(kb0 + hp + (size_t)(s0 + ji * 16 + r) * 64 + 32 + q4 * 8);
    }

    f32x4 sc[4];
    #pragma unroll
    for (int ji = 0; ji < 4; ++ji) {
      f32x4 t = (f32x4){0.f, 0.f, 0.f, 0.f};
      t = __builtin_amdgcn_mfma_f32_16x16x32_bf16(qf0, kf[2 * ji], t, 0, 0, 0);
      t = __builtin_amdgcn_mfma_f32_16x16x32_bf16(qf1, kf[2 * ji + 1], t, 0, 0, 0);
      sc[ji] = t;
    }
    #pragma unroll
    for (int rr = 0; rr < 4; ++rr) {
      float iv = invZ[hh][wv * 16 + q4 * 4 + rr];
      #pragma unroll
      for (int ji = 0; ji < 4; ++ji)
        wacc[ji][rr] += __expf(sc[ji][rr]) * iv;
    }

    qf0 = qn0; qf1 = qn1;
    #pragma unroll
    for (int i = 0; i < 8; ++i) kf[i] = kn[i];
  }

  #pragma unroll
  for (int ji = 0; ji < 4; ++ji)
    #pragma unroll
    for (int rr = 0; rr < 4; ++rr) {
      int row = lw + q4 * 4 + rr;
      int col = s0 + ji * 16 + r;
      out_w[(size_t)n * 1048576 + (size_t)row * 1024 + col] = wacc[ji][rr];
    }
}

// ---------------------------------------------------------------------------
// Kernel 4: output projection, 128x128 LDS-tiled. Unchanged from round 7.
// ---------------------------------------------------------------------------
__global__ __launch_bounds__(256) void out_gemm(
    const u16* __restrict__ ctx, const u16* __restrict__ W,
    const float* __restrict__ bias, float* __restrict__ out)
{
  __shared__ __align__(16) u16 As[128 * 40];
  __shared__ __align__(16) u16 Bs[128 * 40];

  const int tid  = threadIdx.x;
  const int wave = tid >> 6;
  const int lane = tid & 63;
  const int r    = lane & 15;
  const int q4   = lane >> 4;
  const int wm   = wave >> 1;
  const int wn   = wave & 1;

  const int j0 = blockIdx.x * 128;
  const int m0 = blockIdx.y * 128;

  const int trow = tid >> 2;
  const int tcol = (tid & 3) * 8;

  f32x4 acc[4][4];
  #pragma unroll
  for (int a = 0; a < 4; ++a)
    #pragma unroll
    for (int b = 0; b < 4; ++b)
      acc[a][b] = (f32x4){0.f, 0.f, 0.f, 0.f};

  for (int kk = 0; kk < 1024; kk += 32) {
    short8 a0 = *(const short8*)(ctx + (size_t)(m0 + trow) * 1024 + kk + tcol);
    short8 a1 = *(const short8*)(ctx + (size_t)(m0 + 64 + trow) * 1024 + kk + tcol);
    short8 b0 = *(const short8*)(W + (size_t)(j0 + trow) * 1024 + kk + tcol);
    short8 b1 = *(const short8*)(W + (size_t)(j0 + 64 + trow) * 1024 + kk + tcol);
    __syncthreads();
    *(short8*)(As + trow * 40 + tcol) = a0;
    *(short8*)(As + (64 + trow) * 40 + tcol) = a1;
    *(short8*)(Bs + trow * 40 + tcol) = b0;
    *(short8*)(Bs + (64 + trow) * 40 + tcol) = b1;
    __syncthreads();

    const u16* Ab = As + (wm * 64) * 40;
    const u16* Bb = Bs + (wn * 64) * 40;
    short8 af[4], bf[4];
    #pragma unroll
    for (int mi = 0; mi < 4; ++mi)
      af[mi] = *(const short8*)(Ab + (mi * 16 + r) * 40 + q4 * 8);
    #pragma unroll
    for (int ji = 0; ji < 4; ++ji)
      bf[ji] = *(const short8*)(Bb + (ji * 16 + r) * 40 + q4 * 8);
    #pragma unroll
    for (int mi = 0; mi < 4; ++mi)
      #pragma unroll
      for (int ji = 0; ji < 4; ++ji)
        acc[mi][ji] = __builtin_amdgcn_mfma_f32_16x16x32_bf16(af[mi], bf[ji], acc[mi][ji], 0, 0, 0);
  }

  #pragma unroll
  for (int mi = 0; mi < 4; ++mi) {
    #pragma unroll
    for (int ji = 0; ji < 4; ++ji) {
      #pragma unroll
      for (int rr = 0; rr < 4; ++rr) {
        int m = m0 + wm * 64 + mi * 16 + q4 * 4 + rr;
        int j = j0 + wn * 64 + ji * 16 + r;
        out[(size_t)m * 1024 + j] = acc[mi][ji][rr] + bias[j];
      }
    }
  }
}

// ---------------------------------------------------------------------------
extern "C" void kernel_launch(void* const* d_in, const int* in_sizes, int n_in,
                              void* d_out, int out_size, void* d_ws, size_t ws_size,
                              hipStream_t stream) {
  const float* query = (const float*)d_in[0];
  const float* key   = (const float*)d_in[1];
  const float* value = (const float*)d_in[2];
  const float* W_in  = (const float*)d_in[3];
  const float* b_in  = (const float*)d_in[4];
  const float* W_out = (const float*)d_in[5];
  const float* b_out = (const float*)d_in[6];
  float* out = (float*)d_out;

  // ws (~64.3 MB): qb 8 | kb 8 | vb 8 | Wib 6 | Wob 2 | qh 8 | kh 8 | vt 8 | ctx 8 | Z .25
  u16* qb  = (u16*)d_ws;
  u16* kb  = qb  + (size_t)4194304;
  u16* vb  = kb  + (size_t)4194304;
  u16* Wib = vb  + (size_t)4194304;
  u16* Wob = Wib + (size_t)3145728;
  u16* qh  = Wob + (size_t)1048576;
  u16* kh  = qh  + (size_t)4194304;
  u16* vt  = kh  + (size_t)4194304;
  u16* ctx = vt  + (size_t)4194304;
  float* Zbuf = (float*)(ctx + (size_t)4194304);

  convert_bf16<<<dim3(512, 5), 256, 0, stream>>>(query, key, value, W_in, W_out,
                                                 qb, kb, vb, Wib, Wob);
  qkv_gemm<<<dim3(24, 32), 256, 0, stream>>>(qb, kb, vb, Wib, b_in, qh, kh, vt);
  attn_ctx_mfma<<<dim3(16, 64), 256, 0, stream>>>(qh, kh, vt, ctx, Zbuf);
  attn_w_mfma<<<dim3(16, 16, 4), 256, 0, stream>>>(qh, kh, Zbuf, out + (size_t)4194304);
  out_gemm<<<dim3(8, 32), 256, 0, stream>>>(ctx, Wob, b_out, out);
}